// Round 8
// baseline (979.819 us; speedup 1.0000x reference)
//
#include <hip/hip_runtime.h>
#include <hip/hip_bf16.h>
#include <stdint.h>

#define NN 128   // graph nodes N
#define ND 256   // feature dim D

// 16B-granule XOR swizzle, bijective per 16-lane access group on both the
// stage b128 writes and the MFMA b128 reads (verified R7: conflicts 1.5e7 -> 1e6).
#define SWZ(d) ((((d) ^ ((d) >> 2)) & 15) << 3)

typedef __attribute__((ext_vector_type(8))) short short8v;
typedef __attribute__((ext_vector_type(4))) short short4v;
typedef __attribute__((ext_vector_type(4))) float floatx4;
typedef __attribute__((ext_vector_type(4))) unsigned int uint4v;

__device__ __forceinline__ unsigned short f2bf(float x){
  unsigned u = __float_as_uint(x);
  u += 0x7FFF + ((u >> 16) & 1);   // round-to-nearest-even
  return (unsigned short)(u >> 16);
}
__device__ __forceinline__ float bf2f(unsigned short h){
  return __uint_as_float(((unsigned)h) << 16);
}
__device__ __forceinline__ unsigned pk2(float a, float b){
  float2 t; t.x = a; t.y = b;
  __hip_bfloat162 hh = __float22bfloat162_rn(t);
  unsigned r;
  __builtin_memcpy(&r, &hh, 4);
  return r;
}
__device__ __forceinline__ void gload_lds16(const void* g, void* l){
  // direct HBM->LDS DMA, 16B/lane; LDS dest = wave-uniform base + lane*16
  __builtin_amdgcn_global_load_lds(
      (const __attribute__((address_space(1))) unsigned int*)g,
      (__attribute__((address_space(3))) unsigned int*)l, 16, 0, 0);
}

// ws: Abf[256][128] bf16 (rows 0..127 = origin*adj_in ; 128..255 = origin^T*adj_out),
// WgT[8][4][16][8] bf16 gate-weight B-fragments (cols j=0:gw 1:ogw 2:lw, rest 0).
__global__ void prep_A(const float* __restrict__ adj_in, const float* __restrict__ adj_out,
                       const float* __restrict__ gw, const float* __restrict__ ogw,
                       const float* __restrict__ lw, unsigned short* __restrict__ Abf,
                       int do_wgt){
  int idx = blockIdx.x * 256 + threadIdx.x;   // 0..36863
  if (idx < 32768){
    int m = idx >> 7, n = idx & 127;
    float v;
    if (m < NN){
      float a = adj_in[m * NN + n];
      v = (a <= 0.f) ? a * a : a;               // origin(a)*a
    } else {
      int mm = m - NN;
      float t = adj_in[n * NN + mm];            // origin^T[mm][n] = f(adj_in[n][mm])
      float o = (t <= 0.f) ? t : 1.f;
      v = o * adj_out[mm * NN + n];
    }
    Abf[idx] = f2bf(v);
  } else if (idx < 32768 + 4096 && do_wgt){
    int t   = idx - 32768;
    int j   = t & 7, m16 = (t >> 3) & 15, g = (t >> 7) & 3, kc = t >> 9;
    int d   = kc * 32 + 8 * g + j;
    float v = (m16 == 0) ? gw[d] : (m16 == 1) ? ogw[d] : (m16 == 2) ? lw[d] : 0.f;
    Abf[idx] = f2bf(v);
  }
}

// ---- PASS 1: per batch: gates + transpose/convert H -> pre-swizzled bf16 Htg ----
__global__ __launch_bounds__(256, 2) void pass1(
    const float* __restrict__ H, const unsigned short* __restrict__ WgT,
    const float* __restrict__ bg, const float* __restrict__ obg,
    unsigned short* __restrict__ Htg, float* __restrict__ sigG)
{
  __shared__ __align__(16) unsigned short Ht[ND * NN];   // 64 KB, [d][n^SWZ(d)]

  const int tid = threadIdx.x;
  const int w = tid >> 6, lane = tid & 63, g = lane >> 4, m16 = lane & 15;
  const int b = blockIdx.x;
  const float* Hb = H + (size_t)b * NN * ND;

  // gates via MFMA (D-map: row=4g+r -> node, col=m16 -> gate j)
  floatx4 ga[2];
  ga[0] = (floatx4){0.f,0.f,0.f,0.f};
  ga[1] = (floatx4){0.f,0.f,0.f,0.f};
  #pragma unroll
  for (int c = 0; c < 8; ++c){
    const int k0 = 32 * c + 8 * g;
    const short8v wv = *(const short8v*)&WgT[((c * 4 + g) * 16 + m16) * 8];
    #pragma unroll
    for (int rs = 0; rs < 2; ++rs){
      const int row = 64 * rs + 16 * w + m16;
      const floatx4 f0 = *(const floatx4*)(Hb + (size_t)row * ND + k0);
      const floatx4 f1 = *(const floatx4*)(Hb + (size_t)row * ND + k0 + 4);
      uint4v au;
      au[0] = pk2(f0[0], f0[1]); au[1] = pk2(f0[2], f0[3]);
      au[2] = pk2(f1[0], f1[1]); au[3] = pk2(f1[2], f1[3]);
      short8v af;
      __builtin_memcpy(&af, &au, 16);
      ga[rs] = __builtin_amdgcn_mfma_f32_16x16x32_bf16(af, wv, ga[rs], 0, 0, 0);
    }
  }
  if (m16 < 3){
    #pragma unroll
    for (int rs = 0; rs < 2; ++rs){
      #pragma unroll
      for (int r = 0; r < 4; ++r){
        const int n = 64 * rs + 16 * w + 4 * g + r;
        float x = ga[rs][r];
        if (m16 == 0)      x += bg[n];
        else if (m16 == 1) x += obg[n];
        sigG[(size_t)b * 384 + m16 * NN + n] = 1.f / (1.f + __expf(-x));
      }
    }
  }

  // stage all 256 d rows: Ht[d][n^SWZ(d)] = bf16(H[n][d])
  const int n0 = 8 * (4 * w + g);   // group owns rows n0..n0+7
  #pragma unroll
  for (int dq = 0; dq < 4; ++dq){
    const int dl0 = 64 * dq + 4 * m16;
    floatx4 rr[8];
    #pragma unroll
    for (int ro = 0; ro < 8; ++ro)
      rr[ro] = *(const floatx4*)(Hb + (size_t)(n0 + ro) * ND + dl0);
    #pragma unroll
    for (int j = 0; j < 4; ++j){
      const int d = dl0 + j;
      uint4v pv;
      pv[0] = pk2(rr[0][j], rr[1][j]);
      pv[1] = pk2(rr[2][j], rr[3][j]);
      pv[2] = pk2(rr[4][j], rr[5][j]);
      pv[3] = pk2(rr[6][j], rr[7][j]);
      *(uint4v*)&Ht[d * NN + (n0 ^ SWZ(d))] = pv;
    }
  }
  __syncthreads();

  // linear copy-out (keeps swizzled layout in global -> pass2 DMA stays linear)
  const uint4v* src = (const uint4v*)Ht;
  uint4v*       dst = (uint4v*)(Htg + (size_t)b * 32768);
  #pragma unroll
  for (int i = 0; i < 16; ++i)
    dst[i * 256 + tid] = src[i * 256 + tid];
}

// ---- PASS 2: persistent GEMM; tile = (batch b = tile>>1, d-half h = tile&1) ----
__global__ __launch_bounds__(256, 2) void pass2(
    const unsigned short* __restrict__ Htg, const unsigned short* __restrict__ Abf,
    const float* __restrict__ sigG, const float* __restrict__ eb,
    const float* __restrict__ oeb, float* __restrict__ Out)
{
  __shared__ __align__(16) unsigned short Hs[2][128 * 128];   // 2 x 32 KB ping-pong

  const int tid = threadIdx.x;
  const int w = tid >> 6, lane = tid & 63, g = lane >> 4, m16 = lane & 15;

  auto stage = [&](int buf, int tile){
    const char* gp = (const char*)Htg + (size_t)tile * 32768;
    char*       lp = (char*)&Hs[buf][0];
    #pragma unroll
    for (int i = 0; i < 8; ++i){
      const int co = w * 8192 + i * 1024;          // wave-uniform chunk base
      gload_lds16(gp + co + lane * 16, lp + co);   // per-lane global, uniform LDS base
    }
  };

  auto compute = [&](int buf, int tile){
    const int b = tile >> 1, h = tile & 1;
    float*       Ob = Out + (size_t)b * NN * ND;
    const float* sg = sigG + (size_t)b * 384;

    #pragma unroll
    for (int half2 = 0; half2 < 2; ++half2){
      floatx4 acc1[2][4], acc2[2][4];
      #pragma unroll
      for (int rs = 0; rs < 2; ++rs)
        #pragma unroll
        for (int i = 0; i < 4; ++i){
          acc1[rs][i] = (floatx4){0.f,0.f,0.f,0.f};
          acc2[rs][i] = (floatx4){0.f,0.f,0.f,0.f};
        }
      __builtin_amdgcn_s_setprio(1);
      #pragma unroll
      for (int k0 = 0; k0 < 128; k0 += 32){
        const int kk = k0 + 8 * g;
        short8v av1[2], av2[2];
        #pragma unroll
        for (int rs = 0; rs < 2; ++rs){
          const int m = 64 * rs + 16 * w + m16;
          av1[rs] = *(const short8v*)&Abf[ m        * 128 + kk];
          av2[rs] = *(const short8v*)&Abf[(128 + m) * 128 + kk];
        }
        #pragma unroll
        for (int df2 = 0; df2 < 4; ++df2){
          const int d = 16 * (4 * half2 + df2) + m16;
          const short8v hv = *(const short8v*)&Hs[buf][d * 128 + (kk ^ SWZ(d))];
          #pragma unroll
          for (int rs = 0; rs < 2; ++rs){
            acc1[rs][df2] = __builtin_amdgcn_mfma_f32_16x16x32_bf16(hv, av1[rs], acc1[rs][df2], 0, 0, 0);
            acc2[rs][df2] = __builtin_amdgcn_mfma_f32_16x16x32_bf16(hv, av2[rs], acc2[rs][df2], 0, 0, 0);
          }
        }
      }
      __builtin_amdgcn_s_setprio(0);

      #pragma unroll
      for (int rs = 0; rs < 2; ++rs){
        const int arow = 64 * rs + 16 * w + m16;
        const float si = sg[arow];
        const float so = sg[NN + arow];
        const float sl = sg[2 * NN + arow];
        #pragma unroll
        for (int df2 = 0; df2 < 4; ++df2){
          const int dloc  = 16 * (4 * half2 + df2) + 4 * g;
          const int dglob = 128 * h + dloc;
          const floatx4 ebv  = *(const floatx4*)(eb  + arow * ND + dglob);
          const floatx4 oebv = *(const floatx4*)(oeb + arow * ND + dglob);
          floatx4 o;
          #pragma unroll
          for (int r = 0; r < 4; ++r){
            const int d = dloc + r;
            const float hl = bf2f(Hs[buf][d * 128 + (arow ^ SWZ(d))]);
            const float v = (acc1[rs][df2][r] + ebv[r]) * si
                          + (acc2[rs][df2][r] + oebv[r]) * so
                          + hl * sl;
            o[r] = fmaxf(v, 0.f);
          }
          *(floatx4*)(Ob + (size_t)arow * ND + dglob) = o;
        }
      }
    }
  };

  // T3-minimum pipeline: DMA for tile t+1 in flight across all of compute(t)
  int cur = 0;
  stage(0, blockIdx.x);
  __syncthreads();
  #pragma unroll 1
  for (int t = 0; t < 16; ++t){
    const int tile = 512 * t + blockIdx.x;
    if (t < 15) stage(cur ^ 1, tile + 512);
    compute(cur, tile);
    __syncthreads();   // drains DMA (+stores) once per tile; safe, compiler-modeled
    cur ^= 1;
  }
}

// ---- fallback (R1 kernel, 425 us) if ws_size can't hold Htg ----
__global__ __launch_bounds__(512) void gcn_fb(
    const float* __restrict__ H, const unsigned short* __restrict__ Abf,
    const float* __restrict__ eb,  const float* __restrict__ gw,
    const float* __restrict__ bg,  const float* __restrict__ oeb,
    const float* __restrict__ ogw, const float* __restrict__ obg,
    const float* __restrict__ lw,  float* __restrict__ Out)
{
  __shared__ __align__(16) unsigned short Ht[ND * NN];
  __shared__ float sigS[3 * NN];

  const int tid  = threadIdx.x;
  const int wave = tid >> 6;
  const int lane = tid & 63;
  const int g    = lane >> 4;
  const int m16  = lane & 15;
  const int b    = blockIdx.x;
  const float* Hb = H   + (size_t)b * NN * ND;
  float*       Ob = Out + (size_t)b * NN * ND;

  for (int pi = 0; pi < 2; ++pi){
    int p = 8 * wave + 4 * pi + g;
    int n = 2 * p;
    float s0=0.f,s1=0.f,s2=0.f,s3=0.f,s4=0.f,s5=0.f;
    #pragma unroll
    for (int di = 0; di < 8; ++di){
      int d = 32 * di + 2 * m16;
      float2 a  = *(const float2*)(Hb + n * ND + d);
      float2 c  = *(const float2*)(Hb + (n + 1) * ND + d);
      float2 w0 = *(const float2*)(gw  + d);
      float2 w1 = *(const float2*)(ogw + d);
      float2 w2 = *(const float2*)(lw  + d);
      s0 += a.x * w0.x + a.y * w0.y;
      s1 += a.x * w1.x + a.y * w1.y;
      s2 += a.x * w2.x + a.y * w2.y;
      s3 += c.x * w0.x + c.y * w0.y;
      s4 += c.x * w1.x + c.y * w1.y;
      s5 += c.x * w2.x + c.y * w2.y;
      unsigned v0 = (unsigned)f2bf(a.x) | ((unsigned)f2bf(c.x) << 16);
      unsigned v1 = (unsigned)f2bf(a.y) | ((unsigned)f2bf(c.y) << 16);
      int i0 = d       * NN + (n ^ (( d      & 7) << 3));
      int i1 = (d + 1) * NN + (n ^ (((d + 1) & 7) << 3));
      *(unsigned*)&Ht[i0] = v0;
      *(unsigned*)&Ht[i1] = v1;
    }
    #pragma unroll
    for (int m = 1; m < 16; m <<= 1){
      s0 += __shfl_xor(s0, m, 64);
      s1 += __shfl_xor(s1, m, 64);
      s2 += __shfl_xor(s2, m, 64);
      s3 += __shfl_xor(s3, m, 64);
      s4 += __shfl_xor(s4, m, 64);
      s5 += __shfl_xor(s5, m, 64);
    }
    if (m16 == 0){
      float gi0 = s0 + bg[n],     go0 = s1 + obg[n];
      float gi1 = s3 + bg[n + 1], go1 = s4 + obg[n + 1];
      sigS[n]              = 1.f / (1.f + __expf(-gi0));
      sigS[NN + n]         = 1.f / (1.f + __expf(-go0));
      sigS[2 * NN + n]     = 1.f / (1.f + __expf(-s2));
      sigS[n + 1]          = 1.f / (1.f + __expf(-gi1));
      sigS[NN + n + 1]     = 1.f / (1.f + __expf(-go1));
      sigS[2 * NN + n + 1] = 1.f / (1.f + __expf(-s5));
    }
  }
  __syncthreads();

  const int mrow = 16 * wave + m16;
  float si_[4], so_[4], sl_[4];
  #pragma unroll
  for (int r = 0; r < 4; ++r){
    int mm = 16 * wave + 4 * g + r;
    si_[r] = sigS[mm];
    so_[r] = sigS[NN + mm];
    sl_[r] = sigS[2 * NN + mm];
  }

  const floatx4 zz = {0.f, 0.f, 0.f, 0.f};
  #pragma unroll
  for (int pass = 0; pass < 2; ++pass){
    const int dbase = 128 * pass;
    floatx4 acc1[8], acc2[8];
    #pragma unroll
    for (int i = 0; i < 8; ++i){ acc1[i] = zz; acc2[i] = zz; }

    #pragma unroll
    for (int k0 = 0; k0 < 128; k0 += 32){
      const int kk = k0 + 8 * g;
      short8v a1 = *(const short8v*)&Abf[ mrow        * 128 + kk];
      short8v a2 = *(const short8v*)&Abf[(128 + mrow) * 128 + kk];
      #pragma unroll
      for (int df = 0; df < 8; ++df){
        int d = dbase + 16 * df + m16;
        const short8v bv = *(const short8v*)&Ht[d * NN + (kk ^ ((d & 7) << 3))];
        acc1[df] = __builtin_amdgcn_mfma_f32_16x16x32_bf16(a1, bv, acc1[df], 0, 0, 0);
        acc2[df] = __builtin_amdgcn_mfma_f32_16x16x32_bf16(a2, bv, acc2[df], 0, 0, 0);
      }
    }

    #pragma unroll
    for (int df = 0; df < 8; ++df){
      int d  = dbase + 16 * df + m16;
      int m0 = 16 * wave + 4 * g;
      short4v hv = *(const short4v*)&Ht[d * NN + (m0 ^ ((d & 7) << 3))];
      #pragma unroll
      for (int r = 0; r < 4; ++r){
        int mm = m0 + r;
        float hl = bf2f((unsigned short)hv[r]);
        float v = acc1[df][r] * si_[r] + acc2[df][r] * so_[r] + hl * sl_[r]
                + eb [mm * ND + d] * si_[r]
                + oeb[mm * ND + d] * so_[r];
        Ob[mm * ND + d] = fmaxf(v, 0.f);
      }
    }
  }
}

extern "C" void kernel_launch(void* const* d_in, const int* in_sizes, int n_in,
                              void* d_out, int out_size, void* d_ws, size_t ws_size,
                              hipStream_t stream){
  const float* H    = (const float*)d_in[0];
  const float* ain  = (const float*)d_in[1];
  const float* aout = (const float*)d_in[2];
  const float* eb   = (const float*)d_in[3];
  const float* gwp  = (const float*)d_in[4];
  const float* bgp  = (const float*)d_in[5];
  const float* oebp = (const float*)d_in[6];
  const float* ogwp = (const float*)d_in[7];
  const float* obgp = (const float*)d_in[8];
  const float* lwp  = (const float*)d_in[9];
  unsigned short* Abf = (unsigned short*)d_ws;

  const size_t sig_off = 73728;                       // Abf 64K + WgT 8K
  const size_t htg_off = sig_off + (size_t)4096 * 384 * 4;   // + sigG 6.29 MB
  const size_t need    = htg_off + (size_t)4096 * 32768 * 2; // + Htg 256 MB

  const int do_wgt = (ws_size >= sig_off) ? 1 : 0;
  prep_A<<<144, 256, 0, stream>>>(ain, aout, gwp, ogwp, lwp, Abf, do_wgt);

  if (ws_size >= need){
    float*          sigG = (float*)((char*)d_ws + sig_off);
    unsigned short* Htg  = (unsigned short*)((char*)d_ws + htg_off);
    pass1<<<4096, 256, 0, stream>>>(H, Abf + 32768, bgp, obgp, Htg, sigG);
    pass2<<<512, 256, 0, stream>>>(Htg, Abf, sigG, eb, oebp, (float*)d_out);
  } else {
    gcn_fb<<<4096, 512, 0, stream>>>(H, Abf, eb, gwp, bgp, oebp, ogwp, obgp, lwp,
                                     (float*)d_out);
  }
}

// Round 9
// 409.201 us; speedup vs baseline: 2.3945x; 2.3945x over previous
//
#include <hip/hip_runtime.h>
#include <hip/hip_bf16.h>

#define NN 128   // graph nodes N
#define ND 256   // feature dim D

// 16B-granule XOR swizzle, bijective per 16-lane access group on both the
// stage writes and the MFMA b128 reads (verified R7: conflicts 1.5e7 -> 1e6).
#define SWZ(d) ((((d) ^ ((d) >> 2)) & 15) << 3)

typedef __attribute__((ext_vector_type(8))) short short8v;
typedef __attribute__((ext_vector_type(4))) float floatx4;
typedef __attribute__((ext_vector_type(2))) unsigned int uint2v;
typedef __attribute__((ext_vector_type(4))) unsigned int uint4v;

__device__ __forceinline__ unsigned short f2bf(float x){
  unsigned u = __float_as_uint(x);
  u += 0x7FFF + ((u >> 16) & 1);   // round-to-nearest-even
  return (unsigned short)(u >> 16);
}
__device__ __forceinline__ float bf2f(unsigned short h){
  return __uint_as_float(((unsigned)h) << 16);
}
__device__ __forceinline__ unsigned pk2(float a, float b){
  float2 t; t.x = a; t.y = b;
  __hip_bfloat162 hh = __float22bfloat162_rn(t);
  unsigned r;
  __builtin_memcpy(&r, &hh, 4);
  return r;
}

// ws: Abf[256][128] bf16 (rows 0..127 = origin*adj_in ; 128..255 = origin^T*adj_out),
// WgT[8][4][16][8] bf16 gate-weight B-fragments (cols j=0:gw 1:ogw 2:lw, rest 0).
__global__ void prep_A(const float* __restrict__ adj_in, const float* __restrict__ adj_out,
                       const float* __restrict__ gw, const float* __restrict__ ogw,
                       const float* __restrict__ lw, unsigned short* __restrict__ Abf){
  int idx = blockIdx.x * 256 + threadIdx.x;   // 0..36863
  if (idx < 32768){
    int m = idx >> 7, n = idx & 127;
    float v;
    if (m < NN){
      float a = adj_in[m * NN + n];
      v = (a <= 0.f) ? a * a : a;               // origin(a)*a
    } else {
      int mm = m - NN;
      float t = adj_in[n * NN + mm];            // origin^T[mm][n] = f(adj_in[n][mm])
      float o = (t <= 0.f) ? t : 1.f;
      v = o * adj_out[mm * NN + n];
    }
    Abf[idx] = f2bf(v);
  } else if (idx < 32768 + 4096){
    int t   = idx - 32768;
    int j   = t & 7, m16 = (t >> 3) & 15, g = (t >> 7) & 3, kc = t >> 9;
    int d   = kc * 32 + 8 * g + j;
    float v = (m16 == 0) ? gw[d] : (m16 == 1) ? ogw[d] : (m16 == 2) ? lw[d] : 0.f;
    Abf[idx] = f2bf(v);
  }
}

__global__ __launch_bounds__(512, 4) void gcn_main(
    const float* __restrict__ H, const unsigned short* __restrict__ Abf,
    const float* __restrict__ eb,  const float* __restrict__ bg,
    const float* __restrict__ oeb, const float* __restrict__ obg,
    float* __restrict__ Out)
{
  // Ht: bf16, [d][n], swizzled: short idx = d*128 + (n ^ SWZ(d))
  __shared__ __align__(16) unsigned short Ht[ND * NN];
  __shared__ float sigS[3 * NN];   // [j*128 + n]: j=0 sig_in, 1 sig_out, 2 sig_loop

  const int tid  = threadIdx.x;
  const int wave = tid >> 6;
  const int lane = tid & 63;
  const int g    = lane >> 4;
  const int m16  = lane & 15;
  // XCD swizzle: 4096 blocks = 8 XCDs x 512 contiguous batches (bijective)
  const int b    = (blockIdx.x & 7) * 512 + (blockIdx.x >> 3);
  const float* Hb = H   + (size_t)b * NN * ND;
  float*       Ob = Out + (size_t)b * NN * ND;
  const unsigned short* WgT = Abf + 32768;

  const int n0   = 4 * (4 * wave + g);   // staging group: owns rows n0..n0+3
  const int arow = 16 * wave + m16;      // gate A-row / epilogue output row m

  // ---- interleaved gates (MFMA) + staging, 2 superslabs of 128 d each ----
  // staging loads issued as 8-deep dwordx4 bursts (128 B/lane in flight).
  floatx4 gacc = {0.f, 0.f, 0.f, 0.f};
  #pragma unroll
  for (int s = 0; s < 2; ++s){
    const int ds0 = 128 * s;
    // burst: 8 x float4 staging loads (rows n0..n0+3, two 64-d quarters)
    floatx4 rr[2][4];
    #pragma unroll
    for (int dq = 0; dq < 2; ++dq)
      #pragma unroll
      for (int ro = 0; ro < 4; ++ro)
        rr[dq][ro] = *(const floatx4*)(Hb + (size_t)(n0 + ro) * ND + ds0 + 64 * dq + 4 * m16);
    // gate part: contracts cols [ds0, ds0+128) against packed gate weights
    #pragma unroll
    for (int t = 0; t < 4; ++t){
      const int k0 = ds0 + 32 * t;
      const short8v wv = *(const short8v*)&WgT[(((k0 >> 5) * 4 + g) * 16 + m16) * 8];
      const floatx4 f0 = *(const floatx4*)(Hb + (size_t)arow * ND + k0 + 8 * g);
      const floatx4 f1 = *(const floatx4*)(Hb + (size_t)arow * ND + k0 + 8 * g + 4);
      uint4v au;
      au[0] = pk2(f0[0], f0[1]); au[1] = pk2(f0[2], f0[3]);
      au[2] = pk2(f1[0], f1[1]); au[3] = pk2(f1[2], f1[3]);
      short8v af;
      __builtin_memcpy(&af, &au, 16);
      gacc = __builtin_amdgcn_mfma_f32_16x16x32_bf16(af, wv, gacc, 0, 0, 0);
    }
    // convert + LDS write the staged quarter-rows
    #pragma unroll
    for (int dq = 0; dq < 2; ++dq){
      #pragma unroll
      for (int j = 0; j < 4; ++j){
        const int d = ds0 + 64 * dq + 4 * m16 + j;
        uint2v pv;
        pv[0] = pk2(rr[dq][0][j], rr[dq][1][j]);
        pv[1] = pk2(rr[dq][2][j], rr[dq][3][j]);
        *(uint2v*)&Ht[d * NN + (n0 ^ SWZ(d))] = pv;   // b64, 8B-aligned
      }
    }
  }
  // finalize gates: D[row=4g+r][col=m16]: gate j=m16 for node n=16*wave+4g+r
  if (m16 < 3){
    #pragma unroll
    for (int r = 0; r < 4; ++r){
      const int n = 16 * wave + 4 * g + r;
      float x = gacc[r];
      if (m16 == 0)      x += bg[n];
      else if (m16 == 1) x += obg[n];
      sigS[m16 * NN + n] = 1.f / (1.f + __expf(-x));
    }
  }
  __syncthreads();

  // ---- GEMM (operand-swapped: D rows = d, cols = m = arow) in 4 passes of 4 df.
  // eb/oeb prefetched BEFORE each k-loop -> loads outstanding during MFMA phase.
  const float si = sigS[arow];
  const float so = sigS[NN + arow];
  const float sl = sigS[2 * NN + arow];

  #pragma unroll
  for (int p = 0; p < 4; ++p){
    // prefetch epilogue operands (8 x dwordx4 per lane in flight)
    floatx4 ebv[4], oebv[4];
    #pragma unroll
    for (int df2 = 0; df2 < 4; ++df2){
      const int dcol = 16 * (4 * p + df2) + 4 * g;
      ebv[df2]  = *(const floatx4*)(eb  + arow * ND + dcol);
      oebv[df2] = *(const floatx4*)(oeb + arow * ND + dcol);
    }

    floatx4 acc1[4], acc2[4];
    #pragma unroll
    for (int i = 0; i < 4; ++i){
      acc1[i] = (floatx4){0.f,0.f,0.f,0.f};
      acc2[i] = (floatx4){0.f,0.f,0.f,0.f};
    }
    __builtin_amdgcn_s_setprio(1);
    #pragma unroll
    for (int k0 = 0; k0 < 128; k0 += 32){
      const int kk = k0 + 8 * g;
      const short8v av1 = *(const short8v*)&Abf[ arow        * 128 + kk];
      const short8v av2 = *(const short8v*)&Abf[(128 + arow) * 128 + kk];
      #pragma unroll
      for (int df2 = 0; df2 < 4; ++df2){
        const int d = 16 * (4 * p + df2) + m16;
        const short8v hv = *(const short8v*)&Ht[d * NN + (kk ^ SWZ(d))];
        acc1[df2] = __builtin_amdgcn_mfma_f32_16x16x32_bf16(hv, av1, acc1[df2], 0, 0, 0);
        acc2[df2] = __builtin_amdgcn_mfma_f32_16x16x32_bf16(hv, av2, acc2[df2], 0, 0, 0);
      }
    }
    __builtin_amdgcn_s_setprio(0);

    #pragma unroll
    for (int df2 = 0; df2 < 4; ++df2){
      const int dcol = 16 * (4 * p + df2) + 4 * g;   // D rows d = dcol + r, col m = arow
      floatx4 o;
      #pragma unroll
      for (int r = 0; r < 4; ++r){
        const int d = dcol + r;
        const float hl = bf2f(Ht[d * NN + (arow ^ SWZ(d))]);  // H[arow][d] from LDS
        const float v = (acc1[df2][r] + ebv[df2][r]) * si
                      + (acc2[df2][r] + oebv[df2][r]) * so
                      + hl * sl;
        o[r] = fmaxf(v, 0.f);
      }
      *(floatx4*)(Ob + (size_t)arow * ND + dcol) = o;   // plain store (nt inflated WRITE)
    }
  }
}

extern "C" void kernel_launch(void* const* d_in, const int* in_sizes, int n_in,
                              void* d_out, int out_size, void* d_ws, size_t ws_size,
                              hipStream_t stream){
  const float* H    = (const float*)d_in[0];
  const float* ain  = (const float*)d_in[1];
  const float* aout = (const float*)d_in[2];
  const float* eb   = (const float*)d_in[3];
  const float* gwp  = (const float*)d_in[4];
  const float* bgp  = (const float*)d_in[5];
  const float* oebp = (const float*)d_in[6];
  const float* ogwp = (const float*)d_in[7];
  const float* obgp = (const float*)d_in[8];
  const float* lwp  = (const float*)d_in[9];
  unsigned short* Abf = (unsigned short*)d_ws;   // 64 KB Abf + 8 KB WgT

  prep_A<<<144, 256, 0, stream>>>(ain, aout, gwp, ogwp, lwp, Abf);
  gcn_main<<<4096, 512, 0, stream>>>(H, Abf, eb, bgp, oebp, obgp, (float*)d_out);
}